// Round 1
// baseline (2870.085 us; speedup 1.0000x reference)
//
#include <hip/hip_runtime.h>
#include <math.h>

#define NPTS 524288
#define H 128
#define NB 55
#define NL 59
#define BLK 256

__device__ __forceinline__ float sp_act(float x) {
    // softplus = logaddexp(x, 0) = max(x,0) + log1p(exp(-|x|))
    return fmaxf(x, 0.0f) + log1pf(__expf(-fabsf(x)));
}
__device__ __forceinline__ float sigf(float x) {
    return 1.0f / (1.0f + __expf(-x));
}

extern "C" __global__ void __launch_bounds__(BLK, 2)
skin_kernel(const float* __restrict__ xyz, const float* __restrict__ quats,
            const float* __restrict__ tfs, const float* __restrict__ amn,
            const float* __restrict__ amx,
            const float* __restrict__ W0, const float* __restrict__ b0,
            const float* __restrict__ W1, const float* __restrict__ b1,
            const float* __restrict__ W2, const float* __restrict__ b2,
            const float* __restrict__ W3, const float* __restrict__ b3,
            float* __restrict__ out)
{
    // per-thread private stash for chunk-0 layer outputs; [j][tid] layout is
    // bank-conflict-free (lanes contiguous within a row). No barriers needed.
    __shared__ float stash[64][BLK];
    const int tid = threadIdx.x;
    const int n = blockIdx.x * BLK + tid;

    const float x = xyz[3 * n + 0];
    const float y = xyz[3 * n + 1];
    const float z = xyz[3 * n + 2];

    const float xn = 2.0f * (x - amn[0]) / (amx[0] - amn[0]) - 1.0f;
    const float yn = 2.0f * (y - amn[1]) / (amx[1] - amn[1]) - 1.0f;
    const float zn = 2.0f * (z - amn[2]) / (amx[2] - amn[2]) - 1.0f;

    // ---- layer 0: 3 -> 128, softplus ----
    float h[H];
#pragma unroll
    for (int j = 0; j < H; ++j) {
        float a = fmaf(zn, W0[2 * H + j], fmaf(yn, W0[H + j], fmaf(xn, W0[j], b0[j])));
        h[j] = sp_act(a);
    }

    // ---- layers 1 and 2: 128 -> 128, softplus; chunked 64+64 accumulators ----
#pragma unroll 1
    for (int L = 0; L < 2; ++L) {
        const float* __restrict__ W = (L == 0) ? W1 : W2;
        const float* __restrict__ b = (L == 0) ? b1 : b2;
        float acc[64];
        // chunk 0: j = 0..63
#pragma unroll
        for (int j = 0; j < 64; ++j) acc[j] = b[j];
#pragma unroll
        for (int k = 0; k < H; ++k) {
            const float hk = h[k];
#pragma unroll
            for (int j = 0; j < 64; ++j) acc[j] = fmaf(hk, W[k * H + j], acc[j]);
        }
#pragma unroll
        for (int j = 0; j < 64; ++j) stash[j][tid] = sp_act(acc[j]);
        // chunk 1: j = 64..127
#pragma unroll
        for (int j = 0; j < 64; ++j) acc[j] = b[64 + j];
#pragma unroll
        for (int k = 0; k < H; ++k) {
            const float hk = h[k];
#pragma unroll
            for (int j = 0; j < 64; ++j) acc[j] = fmaf(hk, W[k * H + 64 + j], acc[j]);
        }
#pragma unroll
        for (int j = 0; j < 64; ++j) h[64 + j] = sp_act(acc[j]);
#pragma unroll
        for (int j = 0; j < 64; ++j) h[j] = stash[j][tid];
    }

    // ---- layer 3: 128 -> 59 logits (no activation) ----
    float l[NL];
#pragma unroll
    for (int j = 0; j < NL; ++j) l[j] = b3[j];
#pragma unroll
    for (int k = 0; k < H; ++k) {
        const float hk = h[k];
#pragma unroll
        for (int j = 0; j < NL; ++j) l[j] = fmaf(hk, W3[k * NL + j], l[j]);
    }

    // ---- hierarchical softmax ----
    float p[NB];
#define BR(par, ch)                                         \
    do {                                                    \
        float a_ = p[par];                                  \
        float s_ = sigf(l[ch]);                             \
        p[ch] = a_ * s_;                                    \
        p[par] = a_ * (1.0f - s_);                          \
    } while (0)

#define SUB3(par, gt, c0, c1, c2)                                            \
    do {                                                                     \
        float a_ = p[par];                                                   \
        float g_ = sigf(l[gt]);                                              \
        float m_ = fmaxf(l[c0], fmaxf(l[c1], l[c2]));                        \
        float e0_ = __expf(l[c0] - m_);                                      \
        float e1_ = __expf(l[c1] - m_);                                      \
        float e2_ = __expf(l[c2] - m_);                                      \
        float inv_ = a_ * g_ / (e0_ + e1_ + e2_);                            \
        p[c0] = e0_ * inv_;                                                  \
        p[c1] = e1_ * inv_;                                                  \
        p[c2] = e2_ * inv_;                                                  \
        p[par] = a_ * (1.0f - g_);                                           \
    } while (0)

#define SUB5(par, gt, c0, c1, c2, c3, c4)                                    \
    do {                                                                     \
        float a_ = p[par];                                                   \
        float g_ = sigf(l[gt]);                                              \
        float m_ = fmaxf(fmaxf(fmaxf(l[c0], l[c1]), fmaxf(l[c2], l[c3])), l[c4]); \
        float e0_ = __expf(l[c0] - m_);                                      \
        float e1_ = __expf(l[c1] - m_);                                      \
        float e2_ = __expf(l[c2] - m_);                                      \
        float e3_ = __expf(l[c3] - m_);                                      \
        float e4_ = __expf(l[c4] - m_);                                      \
        float inv_ = a_ * g_ / (e0_ + e1_ + e2_ + e3_ + e4_);                \
        p[c0] = e0_ * inv_;                                                  \
        p[c1] = e1_ * inv_;                                                  \
        p[c2] = e2_ * inv_;                                                  \
        p[c3] = e3_ * inv_;                                                  \
        p[c4] = e4_ * inv_;                                                  \
        p[par] = a_ * (1.0f - g_);                                           \
    } while (0)

    {
        float s0_ = sigf(l[0]);
        float m_ = fmaxf(l[1], fmaxf(l[2], l[3]));
        float e1_ = __expf(l[1] - m_);
        float e2_ = __expf(l[2] - m_);
        float e3_ = __expf(l[3] - m_);
        float inv_ = s0_ / (e1_ + e2_ + e3_);
        p[1] = e1_ * inv_;
        p[2] = e2_ * inv_;
        p[3] = e3_ * inv_;
        p[0] = 1.0f - s0_;
    }
    BR(1, 4); BR(2, 5); BR(3, 6);
    BR(4, 7); BR(5, 8); BR(6, 9);
    BR(7, 10); BR(8, 11);
    SUB3(9, 55, 12, 13, 14);
    BR(12, 15);
    BR(13, 16); BR(14, 17);
    BR(16, 18); BR(17, 19);
    BR(18, 20); BR(19, 21);
    SUB3(15, 56, 22, 23, 24);
    SUB5(20, 57, 25, 28, 31, 34, 37);
    SUB5(21, 58, 40, 43, 46, 49, 52);
    BR(25, 26); BR(28, 29); BR(31, 32); BR(34, 35); BR(37, 38);
    BR(26, 27); BR(29, 30); BR(32, 33); BR(35, 36); BR(38, 39);
    BR(40, 41); BR(43, 44); BR(46, 47); BR(49, 50); BR(52, 53);
    BR(41, 42); BR(44, 45); BR(47, 48); BR(50, 51); BR(53, 54);

    // ---- T_fwd = p @ tfs (55 x 16) ----
    float T[16];
#pragma unroll
    for (int e = 0; e < 16; ++e) T[e] = 0.0f;
#pragma unroll
    for (int bb = 0; bb < NB; ++bb) {
        const float pb = p[bb];
#pragma unroll
        for (int e = 0; e < 16; ++e) T[e] = fmaf(pb, tfs[bb * 16 + e], T[e]);
    }

    // ---- x_bar = (T @ [xyz,1])[:3] ----
    const float xb0 = fmaf(T[0], x, fmaf(T[1], y, fmaf(T[2], z, T[3])));
    const float xb1 = fmaf(T[4], x, fmaf(T[5], y, fmaf(T[6], z, T[7])));
    const float xb2 = fmaf(T[8], x, fmaf(T[9], y, fmaf(T[10], z, T[11])));

    // ---- rot_hat from quats ----
    float qr = quats[4 * n + 0];
    float qx = quats[4 * n + 1];
    float qy = quats[4 * n + 2];
    float qz = quats[4 * n + 3];
    {
        float inv = 1.0f / sqrtf(qr * qr + qx * qx + qy * qy + qz * qz);
        qr *= inv; qx *= inv; qy *= inv; qz *= inv;
    }
    const float R00 = 1.0f - 2.0f * (qy * qy + qz * qz);
    const float R01 = 2.0f * (qx * qy - qr * qz);
    const float R02 = 2.0f * (qx * qz + qr * qy);
    const float R10 = 2.0f * (qx * qy + qr * qz);
    const float R11 = 1.0f - 2.0f * (qx * qx + qz * qz);
    const float R12 = 2.0f * (qy * qz - qr * qx);
    const float R20 = 2.0f * (qx * qz - qr * qy);
    const float R21 = 2.0f * (qy * qz + qr * qx);
    const float R22 = 1.0f - 2.0f * (qx * qx + qy * qy);

    // ---- rot_bar = T[:3,:3] @ rot_hat ----
    const float B00 = T[0] * R00 + T[1] * R10 + T[2] * R20;
    const float B01 = T[0] * R01 + T[1] * R11 + T[2] * R21;
    const float B02 = T[0] * R02 + T[1] * R12 + T[2] * R22;
    const float B10 = T[4] * R00 + T[5] * R10 + T[6] * R20;
    const float B11 = T[4] * R01 + T[5] * R11 + T[6] * R21;
    const float B12 = T[4] * R02 + T[5] * R12 + T[6] * R22;
    const float B20 = T[8] * R00 + T[9] * R10 + T[10] * R20;
    const float B21 = T[8] * R01 + T[9] * R11 + T[10] * R21;
    const float B22 = T[8] * R02 + T[9] * R12 + T[10] * R22;

    // ---- mat_to_quat ----
    const float t0 = 1.0f + B00 + B11 + B22;
    const float t1 = 1.0f + B00 - B11 - B22;
    const float t2 = 1.0f - B00 + B11 - B22;
    const float t3 = 1.0f - B00 - B11 + B22;
    const float s0 = 0.5f * rsqrtf(fmaxf(t0, 1e-8f));
    const float s1 = 0.5f * rsqrtf(fmaxf(t1, 1e-8f));
    const float s2 = 0.5f * rsqrtf(fmaxf(t2, 1e-8f));
    const float s3 = 0.5f * rsqrtf(fmaxf(t3, 1e-8f));
    const float q0w = t0 * s0, q0x = (B21 - B12) * s0, q0y = (B02 - B20) * s0, q0z = (B10 - B01) * s0;
    const float q1w = (B21 - B12) * s1, q1x = t1 * s1, q1y = (B01 + B10) * s1, q1z = (B02 + B20) * s1;
    const float q2w = (B02 - B20) * s2, q2x = (B01 + B10) * s2, q2y = t2 * s2, q2z = (B12 + B21) * s2;
    const float q3w = (B10 - B01) * s3, q3x = (B02 + B20) * s3, q3y = (B12 + B21) * s3, q3z = t3 * s3;

    // first-max-wins argmax (matches jnp.argmax tie behavior)
    int best = 0;
    float tb = t0;
    if (t1 > tb) { best = 1; tb = t1; }
    if (t2 > tb) { best = 2; tb = t2; }
    if (t3 > tb) { best = 3; tb = t3; }

    float Qw = (best == 0) ? q0w : (best == 1) ? q1w : (best == 2) ? q2w : q3w;
    float Qx = (best == 0) ? q0x : (best == 1) ? q1x : (best == 2) ? q2x : q3x;
    float Qy = (best == 0) ? q0y : (best == 1) ? q1y : (best == 2) ? q2y : q3y;
    float Qz = (best == 0) ? q0z : (best == 1) ? q1z : (best == 2) ? q2z : q3z;
    {
        float inv = 1.0f / sqrtf(Qw * Qw + Qx * Qx + Qy * Qy + Qz * Qz);
        Qw *= inv; Qx *= inv; Qy *= inv; Qz *= inv;
    }

    // ---- stores: x_bar (N,3) | rot_bar (N,3,3) | quat_bar (N,4) | T_fwd (N,4,4) ----
    out[3 * n + 0] = xb0;
    out[3 * n + 1] = xb1;
    out[3 * n + 2] = xb2;
    float* rb = out + 3 * (size_t)NPTS;
    rb[9 * n + 0] = B00; rb[9 * n + 1] = B01; rb[9 * n + 2] = B02;
    rb[9 * n + 3] = B10; rb[9 * n + 4] = B11; rb[9 * n + 5] = B12;
    rb[9 * n + 6] = B20; rb[9 * n + 7] = B21; rb[9 * n + 8] = B22;
    float* qb = out + 12 * (size_t)NPTS;
    qb[4 * n + 0] = Qw; qb[4 * n + 1] = Qx; qb[4 * n + 2] = Qy; qb[4 * n + 3] = Qz;
    float* tf = out + 16 * (size_t)NPTS;
#pragma unroll
    for (int e = 0; e < 16; ++e) tf[16 * n + e] = T[e];
}

extern "C" void kernel_launch(void* const* d_in, const int* in_sizes, int n_in,
                              void* d_out, int out_size, void* d_ws, size_t ws_size,
                              hipStream_t stream) {
    const float* xyz = (const float*)d_in[0];
    const float* quats = (const float*)d_in[1];
    const float* tfs = (const float*)d_in[2];
    const float* amn = (const float*)d_in[3];
    const float* amx = (const float*)d_in[4];
    const float* W0 = (const float*)d_in[5];
    const float* b0 = (const float*)d_in[6];
    const float* W1 = (const float*)d_in[7];
    const float* b1 = (const float*)d_in[8];
    const float* W2 = (const float*)d_in[9];
    const float* b2 = (const float*)d_in[10];
    const float* W3 = (const float*)d_in[11];
    const float* b3 = (const float*)d_in[12];
    float* out = (float*)d_out;

    dim3 grid(NPTS / BLK), block(BLK);
    hipLaunchKernelGGL(skin_kernel, grid, block, 0, stream,
                       xyz, quats, tfs, amn, amx, W0, b0, W1, b1, W2, b2, W3, b3, out);
}

// Round 2
// 2441.369 us; speedup vs baseline: 1.1756x; 1.1756x over previous
//
#include <hip/hip_runtime.h>
#include <math.h>

#define NPTS 524288
#define H 128
#define NB 55
#define NL 59
#define BLK 256

// fast approx helpers (precision ~1e-6 rel; output threshold is 0.1 abs)
__device__ __forceinline__ float fast_rcp(float x) { return __builtin_amdgcn_rcpf(x); }
__device__ __forceinline__ float fast_rsq(float x) { return __builtin_amdgcn_rsqf(x); }
__device__ __forceinline__ float sp_act(float x) {
    // softplus = max(x,0) + log(1+exp(-|x|)); exp arg <= 0 so 1+e in (1,2]: no cancellation
    return fmaxf(x, 0.0f) + __logf(1.0f + __expf(-fabsf(x)));
}
__device__ __forceinline__ float sigf(float x) {
    return fast_rcp(1.0f + __expf(-x));
}

extern "C" __global__ void __launch_bounds__(BLK, 1)
skin_kernel(const float* __restrict__ xyz, const float* __restrict__ quats,
            const float* __restrict__ tfs, const float* __restrict__ amn,
            const float* __restrict__ amx,
            const float* __restrict__ W0, const float* __restrict__ b0,
            const float* __restrict__ W1, const float* __restrict__ b1,
            const float* __restrict__ W2, const float* __restrict__ b2,
            const float* __restrict__ W3, const float* __restrict__ b3,
            float* __restrict__ out)
{
    // per-thread private stash for chunk-0 layer outputs; [j][tid] layout is
    // bank-conflict-free (lanes contiguous within a row). No barriers needed.
    __shared__ float stash[64][BLK];
    const int tid = threadIdx.x;
    const int n = blockIdx.x * BLK + tid;

    const float x = xyz[3 * n + 0];
    const float y = xyz[3 * n + 1];
    const float z = xyz[3 * n + 2];

    const float xn = 2.0f * (x - amn[0]) / (amx[0] - amn[0]) - 1.0f;
    const float yn = 2.0f * (y - amn[1]) / (amx[1] - amn[1]) - 1.0f;
    const float zn = 2.0f * (z - amn[2]) / (amx[2] - amn[2]) - 1.0f;

    // ---- layer 0: 3 -> 128, softplus ----
    float h[H];
#pragma unroll
    for (int j = 0; j < H; ++j) {
        float a = fmaf(zn, W0[2 * H + j], fmaf(yn, W0[H + j], fmaf(xn, W0[j], b0[j])));
        h[j] = sp_act(a);
    }

    // ---- layers 1 and 2: 128 -> 128, softplus; chunked 64+64 accumulators ----
    // peak liveness: h[128] + acc[64] + W stream buffer; needs ~230 VGPRs ->
    // __launch_bounds__(BLK,1) so the allocator doesn't cap at 128 and spill.
#pragma unroll 1
    for (int L = 0; L < 2; ++L) {
        const float* __restrict__ W = (L == 0) ? W1 : W2;
        const float* __restrict__ b = (L == 0) ? b1 : b2;
        float acc[64];
        // chunk 0: j = 0..63
#pragma unroll
        for (int j = 0; j < 64; ++j) acc[j] = b[j];
#pragma unroll
        for (int k = 0; k < H; ++k) {
            const float hk = h[k];
#pragma unroll
            for (int j = 0; j < 64; ++j) acc[j] = fmaf(hk, W[k * H + j], acc[j]);
        }
#pragma unroll
        for (int j = 0; j < 64; ++j) stash[j][tid] = sp_act(acc[j]);
        // chunk 1: j = 64..127
#pragma unroll
        for (int j = 0; j < 64; ++j) acc[j] = b[64 + j];
#pragma unroll
        for (int k = 0; k < H; ++k) {
            const float hk = h[k];
#pragma unroll
            for (int j = 0; j < 64; ++j) acc[j] = fmaf(hk, W[k * H + 64 + j], acc[j]);
        }
#pragma unroll
        for (int j = 0; j < 64; ++j) h[64 + j] = sp_act(acc[j]);
#pragma unroll
        for (int j = 0; j < 64; ++j) h[j] = stash[j][tid];
    }

    // ---- layer 3: 128 -> 59 logits (no activation) ----
    float l[NL];
#pragma unroll
    for (int j = 0; j < NL; ++j) l[j] = b3[j];
#pragma unroll
    for (int k = 0; k < H; ++k) {
        const float hk = h[k];
#pragma unroll
        for (int j = 0; j < NL; ++j) l[j] = fmaf(hk, W3[k * NL + j], l[j]);
    }

    // ---- hierarchical softmax ----
    float p[NB];
#define BR(par, ch)                                         \
    do {                                                    \
        float a_ = p[par];                                  \
        float s_ = sigf(l[ch]);                             \
        p[ch] = a_ * s_;                                    \
        p[par] = a_ * (1.0f - s_);                          \
    } while (0)

#define SUB3(par, gt, c0, c1, c2)                                            \
    do {                                                                     \
        float a_ = p[par];                                                   \
        float g_ = sigf(l[gt]);                                              \
        float m_ = fmaxf(l[c0], fmaxf(l[c1], l[c2]));                        \
        float e0_ = __expf(l[c0] - m_);                                      \
        float e1_ = __expf(l[c1] - m_);                                      \
        float e2_ = __expf(l[c2] - m_);                                      \
        float inv_ = a_ * g_ * fast_rcp(e0_ + e1_ + e2_);                    \
        p[c0] = e0_ * inv_;                                                  \
        p[c1] = e1_ * inv_;                                                  \
        p[c2] = e2_ * inv_;                                                  \
        p[par] = a_ * (1.0f - g_);                                           \
    } while (0)

#define SUB5(par, gt, c0, c1, c2, c3, c4)                                    \
    do {                                                                     \
        float a_ = p[par];                                                   \
        float g_ = sigf(l[gt]);                                              \
        float m_ = fmaxf(fmaxf(fmaxf(l[c0], l[c1]), fmaxf(l[c2], l[c3])), l[c4]); \
        float e0_ = __expf(l[c0] - m_);                                      \
        float e1_ = __expf(l[c1] - m_);                                      \
        float e2_ = __expf(l[c2] - m_);                                      \
        float e3_ = __expf(l[c3] - m_);                                      \
        float e4_ = __expf(l[c4] - m_);                                      \
        float inv_ = a_ * g_ * fast_rcp(e0_ + e1_ + e2_ + e3_ + e4_);        \
        p[c0] = e0_ * inv_;                                                  \
        p[c1] = e1_ * inv_;                                                  \
        p[c2] = e2_ * inv_;                                                  \
        p[c3] = e3_ * inv_;                                                  \
        p[c4] = e4_ * inv_;                                                  \
        p[par] = a_ * (1.0f - g_);                                           \
    } while (0)

    {
        float s0_ = sigf(l[0]);
        float m_ = fmaxf(l[1], fmaxf(l[2], l[3]));
        float e1_ = __expf(l[1] - m_);
        float e2_ = __expf(l[2] - m_);
        float e3_ = __expf(l[3] - m_);
        float inv_ = s0_ * fast_rcp(e1_ + e2_ + e3_);
        p[1] = e1_ * inv_;
        p[2] = e2_ * inv_;
        p[3] = e3_ * inv_;
        p[0] = 1.0f - s0_;
    }
    BR(1, 4); BR(2, 5); BR(3, 6);
    BR(4, 7); BR(5, 8); BR(6, 9);
    BR(7, 10); BR(8, 11);
    SUB3(9, 55, 12, 13, 14);
    BR(12, 15);
    BR(13, 16); BR(14, 17);
    BR(16, 18); BR(17, 19);
    BR(18, 20); BR(19, 21);
    SUB3(15, 56, 22, 23, 24);
    SUB5(20, 57, 25, 28, 31, 34, 37);
    SUB5(21, 58, 40, 43, 46, 49, 52);
    BR(25, 26); BR(28, 29); BR(31, 32); BR(34, 35); BR(37, 38);
    BR(26, 27); BR(29, 30); BR(32, 33); BR(35, 36); BR(38, 39);
    BR(40, 41); BR(43, 44); BR(46, 47); BR(49, 50); BR(52, 53);
    BR(41, 42); BR(44, 45); BR(47, 48); BR(50, 51); BR(53, 54);

    // ---- T_fwd = p @ tfs (55 x 16) ----
    float T[16];
#pragma unroll
    for (int e = 0; e < 16; ++e) T[e] = 0.0f;
#pragma unroll
    for (int bb = 0; bb < NB; ++bb) {
        const float pb = p[bb];
#pragma unroll
        for (int e = 0; e < 16; ++e) T[e] = fmaf(pb, tfs[bb * 16 + e], T[e]);
    }

    // ---- x_bar = (T @ [xyz,1])[:3] ----
    const float xb0 = fmaf(T[0], x, fmaf(T[1], y, fmaf(T[2], z, T[3])));
    const float xb1 = fmaf(T[4], x, fmaf(T[5], y, fmaf(T[6], z, T[7])));
    const float xb2 = fmaf(T[8], x, fmaf(T[9], y, fmaf(T[10], z, T[11])));

    // ---- rot_hat from quats ----
    float qr = quats[4 * n + 0];
    float qx = quats[4 * n + 1];
    float qy = quats[4 * n + 2];
    float qz = quats[4 * n + 3];
    {
        float inv = fast_rsq(qr * qr + qx * qx + qy * qy + qz * qz);
        qr *= inv; qx *= inv; qy *= inv; qz *= inv;
    }
    const float R00 = 1.0f - 2.0f * (qy * qy + qz * qz);
    const float R01 = 2.0f * (qx * qy - qr * qz);
    const float R02 = 2.0f * (qx * qz + qr * qy);
    const float R10 = 2.0f * (qx * qy + qr * qz);
    const float R11 = 1.0f - 2.0f * (qx * qx + qz * qz);
    const float R12 = 2.0f * (qy * qz - qr * qx);
    const float R20 = 2.0f * (qx * qz - qr * qy);
    const float R21 = 2.0f * (qy * qz + qr * qx);
    const float R22 = 1.0f - 2.0f * (qx * qx + qy * qy);

    // ---- rot_bar = T[:3,:3] @ rot_hat ----
    const float B00 = T[0] * R00 + T[1] * R10 + T[2] * R20;
    const float B01 = T[0] * R01 + T[1] * R11 + T[2] * R21;
    const float B02 = T[0] * R02 + T[1] * R12 + T[2] * R22;
    const float B10 = T[4] * R00 + T[5] * R10 + T[6] * R20;
    const float B11 = T[4] * R01 + T[5] * R11 + T[6] * R21;
    const float B12 = T[4] * R02 + T[5] * R12 + T[6] * R22;
    const float B20 = T[8] * R00 + T[9] * R10 + T[10] * R20;
    const float B21 = T[8] * R01 + T[9] * R11 + T[10] * R21;
    const float B22 = T[8] * R02 + T[9] * R12 + T[10] * R22;

    // ---- mat_to_quat ----
    const float t0 = 1.0f + B00 + B11 + B22;
    const float t1 = 1.0f + B00 - B11 - B22;
    const float t2 = 1.0f - B00 + B11 - B22;
    const float t3 = 1.0f - B00 - B11 + B22;
    const float s0 = 0.5f * fast_rsq(fmaxf(t0, 1e-8f));
    const float s1 = 0.5f * fast_rsq(fmaxf(t1, 1e-8f));
    const float s2 = 0.5f * fast_rsq(fmaxf(t2, 1e-8f));
    const float s3 = 0.5f * fast_rsq(fmaxf(t3, 1e-8f));
    const float q0w = t0 * s0, q0x = (B21 - B12) * s0, q0y = (B02 - B20) * s0, q0z = (B10 - B01) * s0;
    const float q1w = (B21 - B12) * s1, q1x = t1 * s1, q1y = (B01 + B10) * s1, q1z = (B02 + B20) * s1;
    const float q2w = (B02 - B20) * s2, q2x = (B01 + B10) * s2, q2y = t2 * s2, q2z = (B12 + B21) * s2;
    const float q3w = (B10 - B01) * s3, q3x = (B02 + B20) * s3, q3y = (B12 + B21) * s3, q3z = t3 * s3;

    // first-max-wins argmax (matches jnp.argmax tie behavior)
    int best = 0;
    float tb = t0;
    if (t1 > tb) { best = 1; tb = t1; }
    if (t2 > tb) { best = 2; tb = t2; }
    if (t3 > tb) { best = 3; tb = t3; }

    float Qw = (best == 0) ? q0w : (best == 1) ? q1w : (best == 2) ? q2w : q3w;
    float Qx = (best == 0) ? q0x : (best == 1) ? q1x : (best == 2) ? q2x : q3x;
    float Qy = (best == 0) ? q0y : (best == 1) ? q1y : (best == 2) ? q2y : q3y;
    float Qz = (best == 0) ? q0z : (best == 1) ? q1z : (best == 2) ? q2z : q3z;
    {
        float inv = fast_rsq(Qw * Qw + Qx * Qx + Qy * Qy + Qz * Qz);
        Qw *= inv; Qx *= inv; Qy *= inv; Qz *= inv;
    }

    // ---- stores: x_bar (N,3) | rot_bar (N,3,3) | quat_bar (N,4) | T_fwd (N,4,4) ----
    out[3 * n + 0] = xb0;
    out[3 * n + 1] = xb1;
    out[3 * n + 2] = xb2;
    float* rb = out + 3 * (size_t)NPTS;
    rb[9 * n + 0] = B00; rb[9 * n + 1] = B01; rb[9 * n + 2] = B02;
    rb[9 * n + 3] = B10; rb[9 * n + 4] = B11; rb[9 * n + 5] = B12;
    rb[9 * n + 6] = B20; rb[9 * n + 7] = B21; rb[9 * n + 8] = B22;
    float4* qb = (float4*)(out + 12 * (size_t)NPTS);
    qb[n] = make_float4(Qw, Qx, Qy, Qz);
    float4* tf = (float4*)(out + 16 * (size_t)NPTS);
    tf[4 * n + 0] = make_float4(T[0], T[1], T[2], T[3]);
    tf[4 * n + 1] = make_float4(T[4], T[5], T[6], T[7]);
    tf[4 * n + 2] = make_float4(T[8], T[9], T[10], T[11]);
    tf[4 * n + 3] = make_float4(T[12], T[13], T[14], T[15]);
}

extern "C" void kernel_launch(void* const* d_in, const int* in_sizes, int n_in,
                              void* d_out, int out_size, void* d_ws, size_t ws_size,
                              hipStream_t stream) {
    const float* xyz = (const float*)d_in[0];
    const float* quats = (const float*)d_in[1];
    const float* tfs = (const float*)d_in[2];
    const float* amn = (const float*)d_in[3];
    const float* amx = (const float*)d_in[4];
    const float* W0 = (const float*)d_in[5];
    const float* b0 = (const float*)d_in[6];
    const float* W1 = (const float*)d_in[7];
    const float* b1 = (const float*)d_in[8];
    const float* W2 = (const float*)d_in[9];
    const float* b2 = (const float*)d_in[10];
    const float* W3 = (const float*)d_in[11];
    const float* b3 = (const float*)d_in[12];
    float* out = (float*)d_out;

    dim3 grid(NPTS / BLK), block(BLK);
    hipLaunchKernelGGL(skin_kernel, grid, block, 0, stream,
                       xyz, quats, tfs, amn, amx, W0, b0, W1, b1, W2, b2, W3, b3, out);
}

// Round 5
// 432.520 us; speedup vs baseline: 6.6357x; 5.6445x over previous
//
#include <hip/hip_runtime.h>
#include <hip/hip_bf16.h>
#include <math.h>

#define NPTS 524288
#define H 128
#define NB 55
#define NL 59
#define BLK 256
// LDS row: [hi 256B][lo 256B][pad 16B] = 528B; 528/4=132 == 4 mod 32 -> 2-way bank aliasing (free)
#define ROWB 528

typedef __attribute__((ext_vector_type(8))) short short8;
typedef __attribute__((ext_vector_type(4))) short short4v;
typedef __attribute__((ext_vector_type(4))) float float4v;

// ws layout (bytes)
#define WS_B3P   2048     // [64] f32 (59 real, rest 0)
#define WS_W1HI  4096     // [128 feat][128 k] bf16
#define WS_W1LO  36864
#define WS_W2HI  69632
#define WS_W2LO  102400
#define WS_W3HI  135168   // [64 feat][128 k] bf16 (rows>=59 zero)
#define WS_W3LO  151552

__device__ __forceinline__ float fast_rcp(float x) { return __builtin_amdgcn_rcpf(x); }
__device__ __forceinline__ float fast_rsq(float x) { return __builtin_amdgcn_rsqf(x); }
__device__ __forceinline__ float sp_act(float x) {
    return fmaxf(x, 0.0f) + __logf(1.0f + __expf(-fabsf(x)));
}
__device__ __forceinline__ float sigf(float x) {
    return fast_rcp(1.0f + __expf(-x));
}
__device__ __forceinline__ short f2bf(float f) {
    __hip_bfloat16 h = __float2bfloat16(f);
    union { __hip_bfloat16 b; short s; } u; u.b = h; return u.s;
}
__device__ __forceinline__ float bf2f(short s) {
    union { short s; __hip_bfloat16 b; } u; u.s = s; return __bfloat162float(u.b);
}
__device__ __forceinline__ void split_bf(float v, short& hi, short& lo) {
    hi = f2bf(v);
    lo = f2bf(v - bf2f(hi));
}
__device__ __forceinline__ float4v mfma16(short8 a, short8 b, float4v c) {
    return __builtin_amdgcn_mfma_f32_16x16x32_bf16(a, b, c, 0, 0, 0);
}

// ---- prep: transpose + bf16 hi/lo split of W1/W2/W3 into ws ----
__global__ void prep_kernel(const float* __restrict__ W1, const float* __restrict__ W2,
                            const float* __restrict__ W3, const float* __restrict__ b3,
                            char* __restrict__ ws)
{
    const int tid = blockIdx.x * blockDim.x + threadIdx.x;  // 0..16383
    {
        const int n = tid >> 7, k = tid & 127;
        short hi, lo;
        split_bf(W1[k * H + n], hi, lo);
        ((short*)(ws + WS_W1HI))[n * H + k] = hi;
        ((short*)(ws + WS_W1LO))[n * H + k] = lo;
        split_bf(W2[k * H + n], hi, lo);
        ((short*)(ws + WS_W2HI))[n * H + k] = hi;
        ((short*)(ws + WS_W2LO))[n * H + k] = lo;
    }
    if (tid < 64 * 128) {
        const int n = tid >> 7, k = tid & 127;
        float w = (n < NL) ? W3[k * NL + n] : 0.0f;
        short hi, lo;
        split_bf(w, hi, lo);
        ((short*)(ws + WS_W3HI))[n * H + k] = hi;
        ((short*)(ws + WS_W3LO))[n * H + k] = lo;
    }
    if (tid < 64) {
        ((float*)(ws + WS_B3P))[tid] = (tid < NL) ? b3[tid] : 0.0f;
    }
}

// 128-in MFMA layer with hi/lo-compensated A (weights) and B (activations):
// acc += Ahi*Bhi + Ahi*Blo + Alo*Bhi   (Alo*Blo ~2^-18, dropped)
template<int NFT, bool SOFTPLUS>
__device__ __forceinline__ void mfma_layer(char* lds, int mrow0, int lane,
                                           const short* __restrict__ Whi,
                                           const short* __restrict__ Wlo,
                                           const float* __restrict__ bias)
{
    const int l15 = lane & 15;
    const int g = lane >> 4;
    float4v acc[NFT][4];
#pragma unroll
    for (int ft = 0; ft < NFT; ++ft) {
        float4v bv = *(const float4v*)(bias + ft * 16 + g * 4);
#pragma unroll
        for (int pt = 0; pt < 4; ++pt) acc[ft][pt] = bv;
    }
#pragma unroll
    for (int k0 = 0; k0 < 128; k0 += 32) {
        short8 Bhi[4], Blo[4];
#pragma unroll
        for (int pt = 0; pt < 4; ++pt) {
            const char* rowp = lds + (mrow0 + pt * 16 + l15) * ROWB;
            Bhi[pt] = *(const short8*)(rowp + 2 * k0 + 16 * g);
            Blo[pt] = *(const short8*)(rowp + 256 + 2 * k0 + 16 * g);
        }
#pragma unroll
        for (int ft = 0; ft < NFT; ++ft) {
            short8 Ahi = *(const short8*)(Whi + (ft * 16 + l15) * H + k0 + g * 8);
            short8 Alo = *(const short8*)(Wlo + (ft * 16 + l15) * H + k0 + g * 8);
#pragma unroll
            for (int pt = 0; pt < 4; ++pt) {
                acc[ft][pt] = mfma16(Ahi, Bhi[pt], acc[ft][pt]);
                acc[ft][pt] = mfma16(Ahi, Blo[pt], acc[ft][pt]);
                acc[ft][pt] = mfma16(Alo, Bhi[pt], acc[ft][pt]);
            }
        }
    }
    // all LDS reads issued above; in-place writeback safe (same-wave DS ordering)
#pragma unroll
    for (int ft = 0; ft < NFT; ++ft) {
#pragma unroll
        for (int pt = 0; pt < 4; ++pt) {
            char* rowp = lds + (mrow0 + pt * 16 + l15) * ROWB;
            if constexpr (SOFTPLUS) {
                short4v whi, wlo;
                short h0, h1, h2, h3, l0, l1, l2, l3;
                split_bf(sp_act(acc[ft][pt].x), h0, l0);
                split_bf(sp_act(acc[ft][pt].y), h1, l1);
                split_bf(sp_act(acc[ft][pt].z), h2, l2);
                split_bf(sp_act(acc[ft][pt].w), h3, l3);
                whi.x = h0; whi.y = h1; whi.z = h2; whi.w = h3;
                wlo.x = l0; wlo.y = l1; wlo.z = l2; wlo.w = l3;
                *(short4v*)(rowp + (ft * 16 + g * 4) * 2) = whi;
                *(short4v*)(rowp + 256 + (ft * 16 + g * 4) * 2) = wlo;
            } else {
                *(float4v*)(rowp + (ft * 16 + g * 4) * 4) = acc[ft][pt];
            }
        }
    }
}

__global__ void __launch_bounds__(BLK, 1)
skin_kernel(const float* __restrict__ xyz, const float* __restrict__ quats,
            const float* __restrict__ tfs, const float* __restrict__ amn,
            const float* __restrict__ amx,
            const float* __restrict__ W0, const float* __restrict__ b0,
            const float* __restrict__ b1, const float* __restrict__ b2,
            const char* __restrict__ ws, float* __restrict__ out)
{
    __shared__ __align__(16) char lds[BLK * ROWB];  // 135,168 B (<160 KiB/CU)
    const int tid = threadIdx.x;
    const int lane = tid & 63;
    const int wv = tid >> 6;
    const int mrow0 = wv * 64;
    const int n = blockIdx.x * BLK + tid;

    // ---- layer 0 per-thread fp32: 3 -> 128 softplus, hi/lo bf16 into own LDS row ----
    const float x = xyz[3 * n + 0];
    const float y = xyz[3 * n + 1];
    const float z = xyz[3 * n + 2];
    {
        const float xn = 2.0f * (x - amn[0]) / (amx[0] - amn[0]) - 1.0f;
        const float yn = 2.0f * (y - amn[1]) / (amx[1] - amn[1]) - 1.0f;
        const float zn = 2.0f * (z - amn[2]) / (amx[2] - amn[2]) - 1.0f;
        char* row = lds + tid * ROWB;
#pragma unroll
        for (int jj = 0; jj < H; jj += 8) {
            short8 hp, lp;
#pragma unroll
            for (int u = 0; u < 8; ++u) {
                const int j = jj + u;
                float a = fmaf(zn, W0[2 * H + j], fmaf(yn, W0[H + j], fmaf(xn, W0[j], b0[j])));
                float h = sp_act(a);
                short hi, lo;
                split_bf(h, hi, lo);
                hp[u] = hi; lp[u] = lo;
            }
            *(short8*)(row + 2 * jj) = hp;
            *(short8*)(row + 256 + 2 * jj) = lp;
        }
    }

    // ---- layers 1,2: 128 -> 128 softplus; layer 3: 128 -> 64(59) logits fp32 ----
    mfma_layer<8, true>(lds, mrow0, lane, (const short*)(ws + WS_W1HI),
                        (const short*)(ws + WS_W1LO), b1);
    mfma_layer<8, true>(lds, mrow0, lane, (const short*)(ws + WS_W2HI),
                        (const short*)(ws + WS_W2LO), b2);
    mfma_layer<4, false>(lds, mrow0, lane, (const short*)(ws + WS_W3HI),
                         (const short*)(ws + WS_W3LO), (const float*)(ws + WS_B3P));

    // ---- read back own point's logits ----
    float l[64];
#pragma unroll
    for (int j = 0; j < 16; ++j)
        *(float4v*)&l[4 * j] = *(const float4v*)(lds + tid * ROWB + 16 * j);

    // ---- hierarchical softmax (verified R1/R2) ----
    float p[NB];
#define BR(par, ch)                                         \
    do {                                                    \
        float a_ = p[par];                                  \
        float s_ = sigf(l[ch]);                             \
        p[ch] = a_ * s_;                                    \
        p[par] = a_ * (1.0f - s_);                          \
    } while (0)
#define SUB3(par, gt, c0, c1, c2)                                            \
    do {                                                                     \
        float a_ = p[par];                                                   \
        float g_ = sigf(l[gt]);                                              \
        float m_ = fmaxf(l[c0], fmaxf(l[c1], l[c2]));                        \
        float e0_ = __expf(l[c0] - m_);                                      \
        float e1_ = __expf(l[c1] - m_);                                      \
        float e2_ = __expf(l[c2] - m_);                                      \
        float inv_ = a_ * g_ * fast_rcp(e0_ + e1_ + e2_);                    \
        p[c0] = e0_ * inv_;                                                  \
        p[c1] = e1_ * inv_;                                                  \
        p[c2] = e2_ * inv_;                                                  \
        p[par] = a_ * (1.0f - g_);                                           \
    } while (0)
#define SUB5(par, gt, c0, c1, c2, c3, c4)                                    \
    do {                                                                     \
        float a_ = p[par];                                                   \
        float g_ = sigf(l[gt]);                                              \
        float m_ = fmaxf(fmaxf(fmaxf(l[c0], l[c1]), fmaxf(l[c2], l[c3])), l[c4]); \
        float e0_ = __expf(l[c0] - m_);                                      \
        float e1_ = __expf(l[c1] - m_);                                      \
        float e2_ = __expf(l[c2] - m_);                                      \
        float e3_ = __expf(l[c3] - m_);                                      \
        float e4_ = __expf(l[c4] - m_);                                      \
        float inv_ = a_ * g_ * fast_rcp(e0_ + e1_ + e2_ + e3_ + e4_);        \
        p[c0] = e0_ * inv_;                                                  \
        p[c1] = e1_ * inv_;                                                  \
        p[c2] = e2_ * inv_;                                                  \
        p[c3] = e3_ * inv_;                                                  \
        p[c4] = e4_ * inv_;                                                  \
        p[par] = a_ * (1.0f - g_);                                           \
    } while (0)

    {
        float s0_ = sigf(l[0]);
        float m_ = fmaxf(l[1], fmaxf(l[2], l[3]));
        float e1_ = __expf(l[1] - m_);
        float e2_ = __expf(l[2] - m_);
        float e3_ = __expf(l[3] - m_);
        float inv_ = s0_ * fast_rcp(e1_ + e2_ + e3_);
        p[1] = e1_ * inv_;
        p[2] = e2_ * inv_;
        p[3] = e3_ * inv_;
        p[0] = 1.0f - s0_;
    }
    BR(1, 4); BR(2, 5); BR(3, 6);
    BR(4, 7); BR(5, 8); BR(6, 9);
    BR(7, 10); BR(8, 11);
    SUB3(9, 55, 12, 13, 14);
    BR(12, 15);
    BR(13, 16); BR(14, 17);
    BR(16, 18); BR(17, 19);
    BR(18, 20); BR(19, 21);
    SUB3(15, 56, 22, 23, 24);
    SUB5(20, 57, 25, 28, 31, 34, 37);
    SUB5(21, 58, 40, 43, 46, 49, 52);
    BR(25, 26); BR(28, 29); BR(31, 32); BR(34, 35); BR(37, 38);
    BR(26, 27); BR(29, 30); BR(32, 33); BR(35, 36); BR(38, 39);
    BR(40, 41); BR(43, 44); BR(46, 47); BR(49, 50); BR(52, 53);
    BR(41, 42); BR(44, 45); BR(47, 48); BR(50, 51); BR(53, 54);

    // ---- T_fwd = p @ tfs ----
    float T[16];
#pragma unroll
    for (int e = 0; e < 16; ++e) T[e] = 0.0f;
#pragma unroll
    for (int bb = 0; bb < NB; ++bb) {
        const float pb = p[bb];
#pragma unroll
        for (int e = 0; e < 16; ++e) T[e] = fmaf(pb, tfs[bb * 16 + e], T[e]);
    }

    const float xb0 = fmaf(T[0], x, fmaf(T[1], y, fmaf(T[2], z, T[3])));
    const float xb1 = fmaf(T[4], x, fmaf(T[5], y, fmaf(T[6], z, T[7])));
    const float xb2 = fmaf(T[8], x, fmaf(T[9], y, fmaf(T[10], z, T[11])));

    float qr = quats[4 * n + 0];
    float qx = quats[4 * n + 1];
    float qy = quats[4 * n + 2];
    float qz = quats[4 * n + 3];
    {
        float inv = fast_rsq(qr * qr + qx * qx + qy * qy + qz * qz);
        qr *= inv; qx *= inv; qy *= inv; qz *= inv;
    }
    const float R00 = 1.0f - 2.0f * (qy * qy + qz * qz);
    const float R01 = 2.0f * (qx * qy - qr * qz);
    const float R02 = 2.0f * (qx * qz + qr * qy);
    const float R10 = 2.0f * (qx * qy + qr * qz);
    const float R11 = 1.0f - 2.0f * (qx * qx + qz * qz);
    const float R12 = 2.0f * (qy * qz - qr * qx);
    const float R20 = 2.0f * (qx * qz - qr * qy);
    const float R21 = 2.0f * (qy * qz + qr * qx);
    const float R22 = 1.0f - 2.0f * (qx * qx + qy * qy);

    const float B00 = T[0] * R00 + T[1] * R10 + T[2] * R20;
    const float B01 = T[0] * R01 + T[1] * R11 + T[2] * R21;
    const float B02 = T[0] * R02 + T[1] * R12 + T[2] * R22;
    const float B10 = T[4] * R00 + T[5] * R10 + T[6] * R20;
    const float B11 = T[4] * R01 + T[5] * R11 + T[6] * R21;
    const float B12 = T[4] * R02 + T[5] * R12 + T[6] * R22;
    const float B20 = T[8] * R00 + T[9] * R10 + T[10] * R20;
    const float B21 = T[8] * R01 + T[9] * R11 + T[10] * R21;
    const float B22 = T[8] * R02 + T[9] * R12 + T[10] * R22;

    const float t0 = 1.0f + B00 + B11 + B22;
    const float t1 = 1.0f + B00 - B11 - B22;
    const float t2 = 1.0f - B00 + B11 - B22;
    const float t3 = 1.0f - B00 - B11 + B22;
    const float s0 = 0.5f * fast_rsq(fmaxf(t0, 1e-8f));
    const float s1 = 0.5f * fast_rsq(fmaxf(t1, 1e-8f));
    const float s2 = 0.5f * fast_rsq(fmaxf(t2, 1e-8f));
    const float s3 = 0.5f * fast_rsq(fmaxf(t3, 1e-8f));
    const float q0w = t0 * s0, q0x = (B21 - B12) * s0, q0y = (B02 - B20) * s0, q0z = (B10 - B01) * s0;
    const float q1w = (B21 - B12) * s1, q1x = t1 * s1, q1y = (B01 + B10) * s1, q1z = (B02 + B20) * s1;
    const float q2w = (B02 - B20) * s2, q2x = (B01 + B10) * s2, q2y = t2 * s2, q2z = (B12 + B21) * s2;
    const float q3w = (B10 - B01) * s3, q3x = (B02 + B20) * s3, q3y = (B12 + B21) * s3, q3z = t3 * s3;

    int best = 0;
    float tb = t0;
    if (t1 > tb) { best = 1; tb = t1; }
    if (t2 > tb) { best = 2; tb = t2; }
    if (t3 > tb) { best = 3; tb = t3; }

    float Qw = (best == 0) ? q0w : (best == 1) ? q1w : (best == 2) ? q2w : q3w;
    float Qx = (best == 0) ? q0x : (best == 1) ? q1x : (best == 2) ? q2x : q3x;
    float Qy = (best == 0) ? q0y : (best == 1) ? q1y : (best == 2) ? q2y : q3y;
    float Qz = (best == 0) ? q0z : (best == 1) ? q1z : (best == 2) ? q2z : q3z;
    {
        float inv = fast_rsq(Qw * Qw + Qx * Qx + Qy * Qy + Qz * Qz);
        Qw *= inv; Qx *= inv; Qy *= inv; Qz *= inv;
    }

    out[3 * n + 0] = xb0;
    out[3 * n + 1] = xb1;
    out[3 * n + 2] = xb2;
    float* rb = out + 3 * (size_t)NPTS;
    rb[9 * n + 0] = B00; rb[9 * n + 1] = B01; rb[9 * n + 2] = B02;
    rb[9 * n + 3] = B10; rb[9 * n + 4] = B11; rb[9 * n + 5] = B12;
    rb[9 * n + 6] = B20; rb[9 * n + 7] = B21; rb[9 * n + 8] = B22;
    float4* qb = (float4*)(out + 12 * (size_t)NPTS);
    qb[n] = make_float4(Qw, Qx, Qy, Qz);
    float4* tf = (float4*)(out + 16 * (size_t)NPTS);
    tf[4 * n + 0] = make_float4(T[0], T[1], T[2], T[3]);
    tf[4 * n + 1] = make_float4(T[4], T[5], T[6], T[7]);
    tf[4 * n + 2] = make_float4(T[8], T[9], T[10], T[11]);
    tf[4 * n + 3] = make_float4(T[12], T[13], T[14], T[15]);
}

extern "C" void kernel_launch(void* const* d_in, const int* in_sizes, int n_in,
                              void* d_out, int out_size, void* d_ws, size_t ws_size,
                              hipStream_t stream) {
    const float* xyz = (const float*)d_in[0];
    const float* quats = (const float*)d_in[1];
    const float* tfs = (const float*)d_in[2];
    const float* amn = (const float*)d_in[3];
    const float* amx = (const float*)d_in[4];
    const float* W0 = (const float*)d_in[5];
    const float* b0 = (const float*)d_in[6];
    const float* W1 = (const float*)d_in[7];
    const float* b1 = (const float*)d_in[8];
    const float* W2 = (const float*)d_in[9];
    const float* b2 = (const float*)d_in[10];
    const float* W3 = (const float*)d_in[11];
    const float* b3 = (const float*)d_in[12];
    float* out = (float*)d_out;
    char* ws = (char*)d_ws;

    hipLaunchKernelGGL(prep_kernel, dim3(64), dim3(256), 0, stream, W1, W2, W3, b3, ws);
    hipLaunchKernelGGL(skin_kernel, dim3(NPTS / BLK), dim3(BLK), 0, stream,
                       xyz, quats, tfs, amn, amx, W0, b0, b1, b2, (const char*)ws, out);
}

// Round 6
// 338.642 us; speedup vs baseline: 8.4753x; 1.2772x over previous
//
#include <hip/hip_runtime.h>
#include <hip/hip_bf16.h>
#include <math.h>

#define NPTS 524288
#define H 128
#define NB 55
#define NL 59
#define BLK 256
// LDS row: [hi 256B][lo 256B][pad 16B] = 528B
#define ROWB 528

typedef __attribute__((ext_vector_type(8))) short short8;
typedef __attribute__((ext_vector_type(4))) short short4v;
typedef __attribute__((ext_vector_type(4))) float float4v;

// ws layout (bytes)
#define WS_TFHI  0        // [16 elem][64 bone] bf16 hi = 2048
#define WS_B3P   2048     // [64] f32 (59 real, rest 0)
#define WS_W1HI  4096     // [128 feat][128 k] bf16
#define WS_W1LO  36864
#define WS_W2HI  69632
#define WS_W2LO  102400
#define WS_W3HI  135168   // [64 feat][128 k] bf16 (rows>=59 zero)
#define WS_W3LO  151552
#define WS_TFLO  167936   // [16 elem][64 bone] bf16 lo = 2048  (total 169,984)

__device__ __forceinline__ float fast_rcp(float x) { return __builtin_amdgcn_rcpf(x); }
__device__ __forceinline__ float fast_rsq(float x) { return __builtin_amdgcn_rsqf(x); }

#define LOG2E 1.44269504f
#define LN2   0.69314718f

// softplus in base-2: ln2 * log2(1 + 2^(x*log2e)); exact->x for large x, ->0 for x<<0
__device__ __forceinline__ float sp_act(float x) {
    float e = __builtin_amdgcn_exp2f(x * LOG2E);
    return LN2 * __builtin_amdgcn_logf(1.0f + e);
}
__device__ __forceinline__ float sigf(float x) {
    float e = __builtin_amdgcn_exp2f(-x * LOG2E);
    return fast_rcp(1.0f + e);
}
__device__ __forceinline__ unsigned f2u(float f) { union { float f; unsigned u; } v; v.f = f; return v.u; }
__device__ __forceinline__ float u2f(unsigned u) { union { unsigned u; float f; } v; v.u = u; return v.f; }
// cheap hi/lo bf16 split via integer rounding; lo captures hi's residual
__device__ __forceinline__ void split_bf(float v, short& hi, short& lo) {
    unsigned uh = (f2u(v) + 0x8000u) & 0xFFFF0000u;
    hi = (short)(uh >> 16);
    float r = v - u2f(uh);
    lo = (short)((f2u(r) + 0x8000u) >> 16);
}
__device__ __forceinline__ float4v mfma16(short8 a, short8 b, float4v c) {
    return __builtin_amdgcn_mfma_f32_16x16x32_bf16(a, b, c, 0, 0, 0);
}

// ---- prep: transpose + bf16 hi/lo split of W1/W2/W3/tfs into ws ----
__global__ void prep_kernel(const float* __restrict__ W1, const float* __restrict__ W2,
                            const float* __restrict__ W3, const float* __restrict__ b3,
                            const float* __restrict__ tfs, char* __restrict__ ws)
{
    const int tid = blockIdx.x * blockDim.x + threadIdx.x;  // 0..16383
    {
        const int n = tid >> 7, k = tid & 127;
        short hi, lo;
        split_bf(W1[k * H + n], hi, lo);
        ((short*)(ws + WS_W1HI))[n * H + k] = hi;
        ((short*)(ws + WS_W1LO))[n * H + k] = lo;
        split_bf(W2[k * H + n], hi, lo);
        ((short*)(ws + WS_W2HI))[n * H + k] = hi;
        ((short*)(ws + WS_W2LO))[n * H + k] = lo;
    }
    if (tid < 64 * 128) {
        const int n = tid >> 7, k = tid & 127;
        float w = (n < NL) ? W3[k * NL + n] : 0.0f;
        short hi, lo;
        split_bf(w, hi, lo);
        ((short*)(ws + WS_W3HI))[n * H + k] = hi;
        ((short*)(ws + WS_W3LO))[n * H + k] = lo;
    }
    if (tid < 16 * 64) {
        const int e = tid >> 6, b = tid & 63;
        float w = (b < NB) ? tfs[b * 16 + e] : 0.0f;
        short hi, lo;
        split_bf(w, hi, lo);
        ((short*)(ws + WS_TFHI))[e * 64 + b] = hi;
        ((short*)(ws + WS_TFLO))[e * 64 + b] = lo;
    }
    if (tid < 64) {
        ((float*)(ws + WS_B3P))[tid] = (tid < NL) ? b3[tid] : 0.0f;
    }
}

// 128-in MFMA layer, hi/lo-compensated A and B: acc += Ahi*Bhi + Ahi*Blo + Alo*Bhi
template<int NFT, bool SOFTPLUS>
__device__ __forceinline__ void mfma_layer(char* lds, int mrow0, int lane,
                                           const short* __restrict__ Whi,
                                           const short* __restrict__ Wlo,
                                           const float* __restrict__ bias)
{
    const int l15 = lane & 15;
    const int g = lane >> 4;
    float4v acc[NFT][4];
#pragma unroll
    for (int ft = 0; ft < NFT; ++ft) {
        float4v bv = *(const float4v*)(bias + ft * 16 + g * 4);
#pragma unroll
        for (int pt = 0; pt < 4; ++pt) acc[ft][pt] = bv;
    }
#pragma unroll
    for (int k0 = 0; k0 < 128; k0 += 32) {
        short8 Bhi[4], Blo[4];
#pragma unroll
        for (int pt = 0; pt < 4; ++pt) {
            const char* rowp = lds + (mrow0 + pt * 16 + l15) * ROWB;
            Bhi[pt] = *(const short8*)(rowp + 2 * k0 + 16 * g);
            Blo[pt] = *(const short8*)(rowp + 256 + 2 * k0 + 16 * g);
        }
#pragma unroll
        for (int ft = 0; ft < NFT; ++ft) {
            short8 Ahi = *(const short8*)(Whi + (ft * 16 + l15) * H + k0 + g * 8);
            short8 Alo = *(const short8*)(Wlo + (ft * 16 + l15) * H + k0 + g * 8);
#pragma unroll
            for (int pt = 0; pt < 4; ++pt) {
                acc[ft][pt] = mfma16(Ahi, Bhi[pt], acc[ft][pt]);
                acc[ft][pt] = mfma16(Ahi, Blo[pt], acc[ft][pt]);
                acc[ft][pt] = mfma16(Alo, Bhi[pt], acc[ft][pt]);
            }
        }
    }
    // all LDS reads issued above; in-place writeback safe (same-wave DS ordering, validated R5)
#pragma unroll
    for (int ft = 0; ft < NFT; ++ft) {
#pragma unroll
        for (int pt = 0; pt < 4; ++pt) {
            char* rowp = lds + (mrow0 + pt * 16 + l15) * ROWB;
            if constexpr (SOFTPLUS) {
                short4v whi, wlo;
                short h0, h1, h2, h3, l0, l1, l2, l3;
                split_bf(sp_act(acc[ft][pt].x), h0, l0);
                split_bf(sp_act(acc[ft][pt].y), h1, l1);
                split_bf(sp_act(acc[ft][pt].z), h2, l2);
                split_bf(sp_act(acc[ft][pt].w), h3, l3);
                whi.x = h0; whi.y = h1; whi.z = h2; whi.w = h3;
                wlo.x = l0; wlo.y = l1; wlo.z = l2; wlo.w = l3;
                *(short4v*)(rowp + (ft * 16 + g * 4) * 2) = whi;
                *(short4v*)(rowp + 256 + (ft * 16 + g * 4) * 2) = wlo;
            } else {
                *(float4v*)(rowp + (ft * 16 + g * 4) * 4) = acc[ft][pt];
            }
        }
    }
}

__global__ void __launch_bounds__(BLK, 1)
skin_kernel(const float* __restrict__ xyz, const float* __restrict__ quats,
            const float* __restrict__ amn, const float* __restrict__ amx,
            const float* __restrict__ W0, const float* __restrict__ b0,
            const float* __restrict__ b1, const float* __restrict__ b2,
            const char* __restrict__ ws, float* __restrict__ out)
{
    __shared__ __align__(16) char lds[BLK * ROWB];  // 135,168 B
    const int tid = threadIdx.x;
    const int lane = tid & 63;
    const int wv = tid >> 6;
    const int l15 = lane & 15;
    const int g = lane >> 4;
    const int mrow0 = wv * 64;
    const int n = blockIdx.x * BLK + tid;

    // ---- layer 0 per-thread fp32: 3 -> 128 softplus, hi/lo bf16 into own LDS row ----
    const float x = xyz[3 * n + 0];
    const float y = xyz[3 * n + 1];
    const float z = xyz[3 * n + 2];
    {
        const float xn = 2.0f * (x - amn[0]) / (amx[0] - amn[0]) - 1.0f;
        const float yn = 2.0f * (y - amn[1]) / (amx[1] - amn[1]) - 1.0f;
        const float zn = 2.0f * (z - amn[2]) / (amx[2] - amn[2]) - 1.0f;
        char* row = lds + tid * ROWB;
#pragma unroll
        for (int jj = 0; jj < H; jj += 8) {
            short8 hp, lp;
#pragma unroll
            for (int u = 0; u < 8; ++u) {
                const int j = jj + u;
                float a = fmaf(zn, W0[2 * H + j], fmaf(yn, W0[H + j], fmaf(xn, W0[j], b0[j])));
                float h = sp_act(a);
                short hi, lo;
                split_bf(h, hi, lo);
                hp[u] = hi; lp[u] = lo;
            }
            *(short8*)(row + 2 * jj) = hp;
            *(short8*)(row + 256 + 2 * jj) = lp;
        }
    }

    // ---- layers 1,2: 128 -> 128 softplus; layer 3: 128 -> 64(59) logits fp32 ----
    mfma_layer<8, true>(lds, mrow0, lane, (const short*)(ws + WS_W1HI),
                        (const short*)(ws + WS_W1LO), b1);
    mfma_layer<8, true>(lds, mrow0, lane, (const short*)(ws + WS_W2HI),
                        (const short*)(ws + WS_W2LO), b2);
    mfma_layer<4, false>(lds, mrow0, lane, (const short*)(ws + WS_W3HI),
                         (const short*)(ws + WS_W3LO), (const float*)(ws + WS_B3P));

    // ---- read back own point's logits ----
    float l[64];
#pragma unroll
    for (int j = 0; j < 16; ++j)
        *(float4v*)&l[4 * j] = *(const float4v*)(lds + tid * ROWB + 16 * j);

    // ---- hierarchical softmax ----
    float p[NB];
#define BR(par, ch)                                         \
    do {                                                    \
        float a_ = p[par];                                  \
        float s_ = sigf(l[ch]);                             \
        p[ch] = a_ * s_;                                    \
        p[par] = a_ * (1.0f - s_);                          \
    } while (0)
#define SUB3(par, gt, c0, c1, c2)                                            \
    do {                                                                     \
        float a_ = p[par];                                                   \
        float g_ = sigf(l[gt]);                                              \
        float m_ = fmaxf(l[c0], fmaxf(l[c1], l[c2]));                        \
        float e0_ = __expf(l[c0] - m_);                                      \
        float e1_ = __expf(l[c1] - m_);                                      \
        float e2_ = __expf(l[c2] - m_);                                      \
        float inv_ = a_ * g_ * fast_rcp(e0_ + e1_ + e2_);                    \
        p[c0] = e0_ * inv_;                                                  \
        p[c1] = e1_ * inv_;                                                  \
        p[c2] = e2_ * inv_;                                                  \
        p[par] = a_ * (1.0f - g_);                                           \
    } while (0)
#define SUB5(par, gt, c0, c1, c2, c3, c4)                                    \
    do {                                                                     \
        float a_ = p[par];                                                   \
        float g_ = sigf(l[gt]);                                              \
        float m_ = fmaxf(fmaxf(fmaxf(l[c0], l[c1]), fmaxf(l[c2], l[c3])), l[c4]); \
        float e0_ = __expf(l[c0] - m_);                                      \
        float e1_ = __expf(l[c1] - m_);                                      \
        float e2_ = __expf(l[c2] - m_);                                      \
        float e3_ = __expf(l[c3] - m_);                                      \
        float e4_ = __expf(l[c4] - m_);                                      \
        float inv_ = a_ * g_ * fast_rcp(e0_ + e1_ + e2_ + e3_ + e4_);        \
        p[c0] = e0_ * inv_;                                                  \
        p[c1] = e1_ * inv_;                                                  \
        p[c2] = e2_ * inv_;                                                  \
        p[c3] = e3_ * inv_;                                                  \
        p[c4] = e4_ * inv_;                                                  \
        p[par] = a_ * (1.0f - g_);                                           \
    } while (0)

    {
        float s0_ = sigf(l[0]);
        float m_ = fmaxf(l[1], fmaxf(l[2], l[3]));
        float e1_ = __expf(l[1] - m_);
        float e2_ = __expf(l[2] - m_);
        float e3_ = __expf(l[3] - m_);
        float inv_ = s0_ * fast_rcp(e1_ + e2_ + e3_);
        p[1] = e1_ * inv_;
        p[2] = e2_ * inv_;
        p[3] = e3_ * inv_;
        p[0] = 1.0f - s0_;
    }
    BR(1, 4); BR(2, 5); BR(3, 6);
    BR(4, 7); BR(5, 8); BR(6, 9);
    BR(7, 10); BR(8, 11);
    SUB3(9, 55, 12, 13, 14);
    BR(12, 15);
    BR(13, 16); BR(14, 17);
    BR(16, 18); BR(17, 19);
    BR(18, 20); BR(19, 21);
    SUB3(15, 56, 22, 23, 24);
    SUB5(20, 57, 25, 28, 31, 34, 37);
    SUB5(21, 58, 40, 43, 46, 49, 52);
    BR(25, 26); BR(28, 29); BR(31, 32); BR(34, 35); BR(37, 38);
    BR(26, 27); BR(29, 30); BR(32, 33); BR(35, 36); BR(38, 39);
    BR(40, 41); BR(43, 44); BR(46, 47); BR(49, 50); BR(52, 53);
    BR(41, 42); BR(44, 45); BR(47, 48); BR(50, 51); BR(53, 54);

    // ---- T_fwd = p @ tfs via MFMA: p hi/lo rows (reuse logit space), A = tfs^T hi/lo ----
    {
        char* row = lds + tid * ROWB;
#pragma unroll
        for (int jj = 0; jj < 64; jj += 8) {
            short8 hp, lp;
#pragma unroll
            for (int u = 0; u < 8; ++u) {
                const int b = jj + u;
                float v = (b < NB) ? p[b] : 0.0f;
                short hi, lo;
                split_bf(v, hi, lo);
                hp[u] = hi; lp[u] = lo;
            }
            *(short8*)(row + 2 * jj) = hp;
            *(short8*)(row + 128 + 2 * jj) = lp;
        }
    }
    {
        const short* Ahi_p = (const short*)(ws + WS_TFHI);
        const short* Alo_p = (const short*)(ws + WS_TFLO);
        float4v acc[4];
#pragma unroll
        for (int pt = 0; pt < 4; ++pt) acc[pt] = (float4v){0.f, 0.f, 0.f, 0.f};
#pragma unroll
        for (int k0 = 0; k0 < 64; k0 += 32) {
            short8 Bhi[4], Blo[4];
#pragma unroll
            for (int pt = 0; pt < 4; ++pt) {
                const char* rowp = lds + (mrow0 + pt * 16 + l15) * ROWB;
                Bhi[pt] = *(const short8*)(rowp + 2 * k0 + 16 * g);
                Blo[pt] = *(const short8*)(rowp + 128 + 2 * k0 + 16 * g);
            }
            short8 Ahi = *(const short8*)(Ahi_p + l15 * 64 + k0 + g * 8);
            short8 Alo = *(const short8*)(Alo_p + l15 * 64 + k0 + g * 8);
#pragma unroll
            for (int pt = 0; pt < 4; ++pt) {
                acc[pt] = mfma16(Ahi, Bhi[pt], acc[pt]);
                acc[pt] = mfma16(Ahi, Blo[pt], acc[pt]);
                acc[pt] = mfma16(Alo, Bhi[pt], acc[pt]);
            }
        }
        // lane holds T[g*4 .. g*4+4) of point l15 per pt tile -> stash at row offset 256
#pragma unroll
        for (int pt = 0; pt < 4; ++pt)
            *(float4v*)(lds + (mrow0 + pt * 16 + l15) * ROWB + 256 + g * 16) = acc[pt];
    }
    float T[16];
#pragma unroll
    for (int j = 0; j < 4; ++j)
        *(float4v*)&T[4 * j] = *(const float4v*)(lds + tid * ROWB + 256 + 16 * j);

    const float xb0 = fmaf(T[0], x, fmaf(T[1], y, fmaf(T[2], z, T[3])));
    const float xb1 = fmaf(T[4], x, fmaf(T[5], y, fmaf(T[6], z, T[7])));
    const float xb2 = fmaf(T[8], x, fmaf(T[9], y, fmaf(T[10], z, T[11])));

    float qr = quats[4 * n + 0];
    float qx = quats[4 * n + 1];
    float qy = quats[4 * n + 2];
    float qz = quats[4 * n + 3];
    {
        float inv = fast_rsq(qr * qr + qx * qx + qy * qy + qz * qz);
        qr *= inv; qx *= inv; qy *= inv; qz *= inv;
    }
    const float R00 = 1.0f - 2.0f * (qy * qy + qz * qz);
    const float R01 = 2.0f * (qx * qy - qr * qz);
    const float R02 = 2.0f * (qx * qz + qr * qy);
    const float R10 = 2.0f * (qx * qy + qr * qz);
    const float R11 = 1.0f - 2.0f * (qx * qx + qz * qz);
    const float R12 = 2.0f * (qy * qz - qr * qx);
    const float R20 = 2.0f * (qx * qz - qr * qy);
    const float R21 = 2.0f * (qy * qz + qr * qx);
    const float R22 = 1.0f - 2.0f * (qx * qx + qy * qy);

    const float B00 = T[0] * R00 + T[1] * R10 + T[2] * R20;
    const float B01 = T[0] * R01 + T[1] * R11 + T[2] * R21;
    const float B02 = T[0] * R02 + T[1] * R12 + T[2] * R22;
    const float B10 = T[4] * R00 + T[5] * R10 + T[6] * R20;
    const float B11 = T[4] * R01 + T[5] * R11 + T[6] * R21;
    const float B12 = T[4] * R02 + T[5] * R12 + T[6] * R22;
    const float B20 = T[8] * R00 + T[9] * R10 + T[10] * R20;
    const float B21 = T[8] * R01 + T[9] * R11 + T[10] * R21;
    const float B22 = T[8] * R02 + T[9] * R12 + T[10] * R22;

    const float t0 = 1.0f + B00 + B11 + B22;
    const float t1 = 1.0f + B00 - B11 - B22;
    const float t2 = 1.0f - B00 + B11 - B22;
    const float t3 = 1.0f - B00 - B11 + B22;
    const float s0 = 0.5f * fast_rsq(fmaxf(t0, 1e-8f));
    const float s1 = 0.5f * fast_rsq(fmaxf(t1, 1e-8f));
    const float s2 = 0.5f * fast_rsq(fmaxf(t2, 1e-8f));
    const float s3 = 0.5f * fast_rsq(fmaxf(t3, 1e-8f));
    const float q0w = t0 * s0, q0x = (B21 - B12) * s0, q0y = (B02 - B20) * s0, q0z = (B10 - B01) * s0;
    const float q1w = (B21 - B12) * s1, q1x = t1 * s1, q1y = (B01 + B10) * s1, q1z = (B02 + B20) * s1;
    const float q2w = (B02 - B20) * s2, q2x = (B01 + B10) * s2, q2y = t2 * s2, q2z = (B12 + B21) * s2;
    const float q3w = (B10 - B01) * s3, q3x = (B02 + B20) * s3, q3y = (B12 + B21) * s3, q3z = t3 * s3;

    int best = 0;
    float tb = t0;
    if (t1 > tb) { best = 1; tb = t1; }
    if (t2 > tb) { best = 2; tb = t2; }
    if (t3 > tb) { best = 3; tb = t3; }

    float Qw = (best == 0) ? q0w : (best == 1) ? q1w : (best == 2) ? q2w : q3w;
    float Qx = (best == 0) ? q0x : (best == 1) ? q1x : (best == 2) ? q2x : q3x;
    float Qy = (best == 0) ? q0y : (best == 1) ? q1y : (best == 2) ? q2y : q3y;
    float Qz = (best == 0) ? q0z : (best == 1) ? q1z : (best == 2) ? q2z : q3z;
    {
        float inv = fast_rsq(Qw * Qw + Qx * Qx + Qy * Qy + Qz * Qz);
        Qw *= inv; Qx *= inv; Qy *= inv; Qz *= inv;
    }

    out[3 * n + 0] = xb0;
    out[3 * n + 1] = xb1;
    out[3 * n + 2] = xb2;
    float* rb = out + 3 * (size_t)NPTS;
    rb[9 * n + 0] = B00; rb[9 * n + 1] = B01; rb[9 * n + 2] = B02;
    rb[9 * n + 3] = B10; rb[9 * n + 4] = B11; rb[9 * n + 5] = B12;
    rb[9 * n + 6] = B20; rb[9 * n + 7] = B21; rb[9 * n + 8] = B22;
    float4* qb = (float4*)(out + 12 * (size_t)NPTS);
    qb[n] = make_float4(Qw, Qx, Qy, Qz);
    float4* tf = (float4*)(out + 16 * (size_t)NPTS);
    tf[4 * n + 0] = make_float4(T[0], T[1], T[2], T[3]);
    tf[4 * n + 1] = make_float4(T[4], T[5], T[6], T[7]);
    tf[4 * n + 2] = make_float4(T[8], T[9], T[10], T[11]);
    tf[4 * n + 3] = make_float4(T[12], T[13], T[14], T[15]);
}

extern "C" void kernel_launch(void* const* d_in, const int* in_sizes, int n_in,
                              void* d_out, int out_size, void* d_ws, size_t ws_size,
                              hipStream_t stream) {
    const float* xyz = (const float*)d_in[0];
    const float* quats = (const float*)d_in[1];
    const float* tfs = (const float*)d_in[2];
    const float* amn = (const float*)d_in[3];
    const float* amx = (const float*)d_in[4];
    const float* W0 = (const float*)d_in[5];
    const float* b0 = (const float*)d_in[6];
    const float* W1 = (const float*)d_in[7];
    const float* b1 = (const float*)d_in[8];
    const float* W2 = (const float*)d_in[9];
    const float* b2 = (const float*)d_in[10];
    const float* W3 = (const float*)d_in[11];
    const float* b3 = (const float*)d_in[12];
    float* out = (float*)d_out;
    char* ws = (char*)d_ws;

    hipLaunchKernelGGL(prep_kernel, dim3(64), dim3(256), 0, stream, W1, W2, W3, b3, tfs, ws);
    hipLaunchKernelGGL(skin_kernel, dim3(NPTS / BLK), dim3(BLK), 0, stream,
                       xyz, quats, amn, amx, W0, b0, b1, b2, (const char*)ws, out);
}

// Round 8
// 332.857 us; speedup vs baseline: 8.6226x; 1.0174x over previous
//
#include <hip/hip_runtime.h>
#include <hip/hip_bf16.h>
#include <math.h>

#define NPTS 524288
#define H 128
#define NB 55
#define NL 59
#define BLK 256
// LDS row: [hi 256B][lo 256B][pad 16B] = 528B; stride/4 == 4 mod 32 -> 2-way bank aliasing (free)
#define ROWB 528

typedef __attribute__((ext_vector_type(8))) short short8;
typedef __attribute__((ext_vector_type(4))) float float4v;
typedef __attribute__((ext_vector_type(2))) unsigned uint2v;

// ws layout (bytes)
#define WS_TFHI  0        // [16 elem][64 bone] bf16 hi = 2048
#define WS_B3P   2048     // [64] f32 (59 real, rest 0)
#define WS_W1HI  4096     // [128 feat][128 k] bf16 (UNSCALED: ln2*log2e = 1)
#define WS_W1LO  36864
#define WS_W2HI  69632
#define WS_W2LO  102400
#define WS_W3HI  135168   // [64 feat][128 k] bf16, W3*ln2 (rows>=59 zero)
#define WS_W3LO  151552
#define WS_TFLO  167936   // [16 elem][64 bone] bf16 lo = 2048
#define WS_W0P   169984   // [128 feat][32 k] bf16, 9-slot hi/lo packing of W0*log2e = 8192

#define LOG2E 1.44269504f
#define LN2   0.69314718f

__device__ __forceinline__ float fast_rcp(float x) { return __builtin_amdgcn_rcpf(x); }
__device__ __forceinline__ float fast_rsq(float x) { return __builtin_amdgcn_rsqf(x); }
// log2-domain softplus: returns log2(1 + 2^x); true softplus = ln2 * this (folded into weights)
__device__ __forceinline__ float sp_log2(float x) {
    return __builtin_amdgcn_logf(1.0f + __builtin_amdgcn_exp2f(x));
}
__device__ __forceinline__ float sigf(float x) {
    return fast_rcp(1.0f + __builtin_amdgcn_exp2f(-x * LOG2E));
}
__device__ __forceinline__ unsigned f2u(float f) { union { float f; unsigned u; } v; v.f = f; return v.u; }
__device__ __forceinline__ float u2f(unsigned u) { union { unsigned u; float f; } v; v.u = u; return v.f; }
__device__ __forceinline__ void split_bf(float v, short& hi, short& lo) {
    unsigned uh = (f2u(v) + 0x8000u) & 0xFFFF0000u;
    hi = (short)(uh >> 16);
    float r = v - u2f(uh);
    lo = (short)((f2u(r) + 0x8000u) >> 16);
}
// pack hi-bf16 of (a,b) into one dword [hi(a) | hi(b)<<16], lo-residual dword likewise.
// NOTE: locals only — clang can't bind refs to ext_vector elements (R4/R7 lesson).
__device__ __forceinline__ void pack2_hl(float a, float b, unsigned& hw, unsigned& lw) {
    unsigned ua = f2u(a) + 0x8000u, ub = f2u(b) + 0x8000u;
    hw = __builtin_amdgcn_perm(ub, ua, 0x07060302u);
    float ra = a - u2f(ua & 0xFFFF0000u);
    float rb = b - u2f(ub & 0xFFFF0000u);
    lw = __builtin_amdgcn_perm(f2u(rb) + 0x8000u, f2u(ra) + 0x8000u, 0x07060302u);
}
__device__ __forceinline__ float4v mfma16(short8 a, short8 b, float4v c) {
    return __builtin_amdgcn_mfma_f32_16x16x32_bf16(a, b, c, 0, 0, 0);
}

// ---- prep: transpose + bf16 hi/lo split of weights into ws (with log2-domain scaling) ----
__global__ void prep_kernel(const float* __restrict__ W0, const float* __restrict__ W1,
                            const float* __restrict__ W2, const float* __restrict__ W3,
                            const float* __restrict__ b3, const float* __restrict__ tfs,
                            char* __restrict__ ws)
{
    const int tid = blockIdx.x * blockDim.x + threadIdx.x;  // 0..16383
    {
        const int n = tid >> 7, k = tid & 127;
        short hi, lo;
        split_bf(W1[k * H + n], hi, lo);
        ((short*)(ws + WS_W1HI))[n * H + k] = hi;
        ((short*)(ws + WS_W1LO))[n * H + k] = lo;
        split_bf(W2[k * H + n], hi, lo);
        ((short*)(ws + WS_W2HI))[n * H + k] = hi;
        ((short*)(ws + WS_W2LO))[n * H + k] = lo;
    }
    if (tid < 64 * 128) {
        const int n = tid >> 7, k = tid & 127;
        float w = (n < NL) ? W3[k * NL + n] * LN2 : 0.0f;   // acts stored in log2 domain
        short hi, lo;
        split_bf(w, hi, lo);
        ((short*)(ws + WS_W3HI))[n * H + k] = hi;
        ((short*)(ws + WS_W3LO))[n * H + k] = lo;
    }
    if (tid < 16 * 64) {
        const int e = tid >> 6, b = tid & 63;
        float w = (b < NB) ? tfs[b * 16 + e] : 0.0f;
        short hi, lo;
        split_bf(w, hi, lo);
        ((short*)(ws + WS_TFHI))[e * 64 + b] = hi;
        ((short*)(ws + WS_TFLO))[e * 64 + b] = lo;
    }
    if (tid < 128 * 32) {
        // W0P 9-slot packing: slots 0-2 = Whi(x,y,z), 3-5 = Whi, 6-8 = Wlo; W0 scaled by log2e
        const int n = tid >> 5, k = tid & 31;
        short s = 0;
        if (k < 9) {
            const int kk = (k < 3) ? k : ((k < 6) ? k - 3 : k - 6);
            short hi, lo;
            split_bf(W0[kk * H + n] * LOG2E, hi, lo);
            s = (k < 6) ? hi : lo;
        }
        ((short*)(ws + WS_W0P))[n * 32 + k] = s;
    }
    if (tid < 64) {
        ((float*)(ws + WS_B3P))[tid] = (tid < NL) ? b3[tid] : 0.0f;
    }
}

// 128-in MFMA layer, hi/lo-compensated A and B: acc += Ahi*Bhi + Ahi*Blo + Alo*Bhi
template<int NFT, bool SOFTPLUS>
__device__ __forceinline__ void mfma_layer(char* lds, int mrow0, int lane,
                                           const short* __restrict__ Whi,
                                           const short* __restrict__ Wlo,
                                           const float* __restrict__ bias, float bscale)
{
    const int l15 = lane & 15;
    const int g = lane >> 4;
    float4v acc[NFT][4];
#pragma unroll
    for (int ft = 0; ft < NFT; ++ft) {
        float4v bv = *(const float4v*)(bias + ft * 16 + g * 4);
        bv *= bscale;
#pragma unroll
        for (int pt = 0; pt < 4; ++pt) acc[ft][pt] = bv;
    }
#pragma unroll
    for (int k0 = 0; k0 < 128; k0 += 32) {
        short8 Bhi[4], Blo[4];
#pragma unroll
        for (int pt = 0; pt < 4; ++pt) {
            const char* rowp = lds + (mrow0 + pt * 16 + l15) * ROWB;
            Bhi[pt] = *(const short8*)(rowp + 2 * k0 + 16 * g);
            Blo[pt] = *(const short8*)(rowp + 256 + 2 * k0 + 16 * g);
        }
#pragma unroll
        for (int ft = 0; ft < NFT; ++ft) {
            short8 Ahi = *(const short8*)(Whi + (ft * 16 + l15) * H + k0 + g * 8);
            short8 Alo = *(const short8*)(Wlo + (ft * 16 + l15) * H + k0 + g * 8);
#pragma unroll
            for (int pt = 0; pt < 4; ++pt) {
                acc[ft][pt] = mfma16(Ahi, Bhi[pt], acc[ft][pt]);
                acc[ft][pt] = mfma16(Ahi, Blo[pt], acc[ft][pt]);
                acc[ft][pt] = mfma16(Alo, Bhi[pt], acc[ft][pt]);
            }
        }
    }
    // all LDS reads issued above; in-place writeback safe (same-wave DS ordering, validated R5/R6)
#pragma unroll
    for (int ft = 0; ft < NFT; ++ft) {
#pragma unroll
        for (int pt = 0; pt < 4; ++pt) {
            char* rowp = lds + (mrow0 + pt * 16 + l15) * ROWB;
            if constexpr (SOFTPLUS) {
                float s0 = sp_log2(acc[ft][pt].x);
                float s1 = sp_log2(acc[ft][pt].y);
                float s2 = sp_log2(acc[ft][pt].z);
                float s3 = sp_log2(acc[ft][pt].w);
                unsigned hx, lx, hy, ly;
                pack2_hl(s0, s1, hx, lx);
                pack2_hl(s2, s3, hy, ly);
                uint2v hw, lw;
                hw.x = hx; hw.y = hy;
                lw.x = lx; lw.y = ly;
                *(uint2v*)(rowp + (ft * 16 + g * 4) * 2) = hw;
                *(uint2v*)(rowp + 256 + (ft * 16 + g * 4) * 2) = lw;
            } else {
                *(float4v*)(rowp + (ft * 16 + g * 4) * 4) = acc[ft][pt];
            }
        }
    }
}

__global__ void __launch_bounds__(BLK, 1)
skin_kernel(const float* __restrict__ xyz, const float* __restrict__ quats,
            const float* __restrict__ amn, const float* __restrict__ amx,
            const float* __restrict__ b0, const float* __restrict__ b1,
            const float* __restrict__ b2, const char* __restrict__ ws,
            float* __restrict__ out)
{
    __shared__ __align__(16) char lds[BLK * ROWB];  // 135,168 B
    const int tid = threadIdx.x;
    const int lane = tid & 63;
    const int wv = tid >> 6;
    const int l15 = lane & 15;
    const int g = lane >> 4;
    const int mrow0 = wv * 64;
    const int n = blockIdx.x * BLK + tid;

    // ---- per-thread: xyz normalize, 9-slot hi/lo B-row for L0 (k=0..31, bytes 0..63) ----
    const float x = xyz[3 * n + 0];
    const float y = xyz[3 * n + 1];
    const float z = xyz[3 * n + 2];
    {
        const float xn = 2.0f * (x - amn[0]) * fast_rcp(amx[0] - amn[0]) - 1.0f;
        const float yn = 2.0f * (y - amn[1]) * fast_rcp(amx[1] - amn[1]) - 1.0f;
        const float zn = 2.0f * (z - amn[2]) * fast_rcp(amx[2] - amn[2]) - 1.0f;
        short xh, xl, yh, yl, zh, zl;
        split_bf(xn, xh, xl);
        split_bf(yn, yh, yl);
        split_bf(zn, zh, zl);
        short8 s0v; short8 zer = {0, 0, 0, 0, 0, 0, 0, 0};
        s0v[0] = xh; s0v[1] = yh; s0v[2] = zh; s0v[3] = xl;
        s0v[4] = yl; s0v[5] = zl; s0v[6] = xh; s0v[7] = yh;
        short8 s1v = zer; s1v[0] = zh;
        char* row = lds + tid * ROWB;
        *(short8*)(row) = s0v;
        *(short8*)(row + 16) = s1v;
        *(short8*)(row + 32) = zer;
        *(short8*)(row + 48) = zer;
    }

    // ---- layer 0 via MFMA: K=32, one MFMA per (ft,pt); A = 9-slot packed W0*log2e ----
    {
        const short* W0p = (const short*)(ws + WS_W0P);
        float4v acc[8][4];
#pragma unroll
        for (int ft = 0; ft < 8; ++ft) {
            float4v bv = *(const float4v*)(b0 + ft * 16 + g * 4);
            bv *= LOG2E;
#pragma unroll
            for (int pt = 0; pt < 4; ++pt) acc[ft][pt] = bv;
        }
        short8 B[4];
#pragma unroll
        for (int pt = 0; pt < 4; ++pt)
            B[pt] = *(const short8*)(lds + (mrow0 + pt * 16 + l15) * ROWB + 16 * g);
#pragma unroll
        for (int ft = 0; ft < 8; ++ft) {
            short8 A = *(const short8*)(W0p + (ft * 16 + l15) * 32 + g * 8);
#pragma unroll
            for (int pt = 0; pt < 4; ++pt)
                acc[ft][pt] = mfma16(A, B[pt], acc[ft][pt]);
        }
#pragma unroll
        for (int ft = 0; ft < 8; ++ft) {
#pragma unroll
            for (int pt = 0; pt < 4; ++pt) {
                char* rowp = lds + (mrow0 + pt * 16 + l15) * ROWB;
                float s0 = sp_log2(acc[ft][pt].x);
                float s1 = sp_log2(acc[ft][pt].y);
                float s2 = sp_log2(acc[ft][pt].z);
                float s3 = sp_log2(acc[ft][pt].w);
                unsigned hx, lx, hy, ly;
                pack2_hl(s0, s1, hx, lx);
                pack2_hl(s2, s3, hy, ly);
                uint2v hw, lw;
                hw.x = hx; hw.y = hy;
                lw.x = lx; lw.y = ly;
                *(uint2v*)(rowp + (ft * 16 + g * 4) * 2) = hw;
                *(uint2v*)(rowp + 256 + (ft * 16 + g * 4) * 2) = lw;
            }
        }
    }

    // ---- layers 1,2: 128 -> 128 softplus(log2); layer 3: 128 -> 64(59) logits fp32 ----
    mfma_layer<8, true>(lds, mrow0, lane, (const short*)(ws + WS_W1HI),
                        (const short*)(ws + WS_W1LO), b1, LOG2E);
    mfma_layer<8, true>(lds, mrow0, lane, (const short*)(ws + WS_W2HI),
                        (const short*)(ws + WS_W2LO), b2, LOG2E);
    mfma_layer<4, false>(lds, mrow0, lane, (const short*)(ws + WS_W3HI),
                         (const short*)(ws + WS_W3LO), (const float*)(ws + WS_B3P), 1.0f);

    // ---- read back own point's logits ----
    float l[64];
#pragma unroll
    for (int j = 0; j < 16; ++j)
        *(float4v*)&l[4 * j] = *(const float4v*)(lds + tid * ROWB + 16 * j);

    // ---- hierarchical softmax ----
    float p[NB];
#define BR(par, ch)                                         \
    do {                                                    \
        float a_ = p[par];                                  \
        float s_ = sigf(l[ch]);                             \
        p[ch] = a_ * s_;                                    \
        p[par] = a_ * (1.0f - s_);                          \
    } while (0)
#define SUB3(par, gt, c0, c1, c2)                                            \
    do {                                                                     \
        float a_ = p[par];                                                   \
        float g_ = sigf(l[gt]);                                              \
        float m_ = fmaxf(l[c0], fmaxf(l[c1], l[c2]));                        \
        float e0_ = __expf(l[c0] - m_);                                      \
        float e1_ = __expf(l[c1] - m_);                                      \
        float e2_ = __expf(l[c2] - m_);                                      \
        float inv_ = a_ * g_ * fast_rcp(e0_ + e1_ + e2_);                    \
        p[c0] = e0_ * inv_;                                                  \
        p[c1] = e1_ * inv_;                                                  \
        p[c2] = e2_ * inv_;                                                  \
        p[par] = a_ * (1.0f - g_);                                           \
    } while (0)
#define SUB5(par, gt, c0, c1, c2, c3, c4)                                    \
    do {                                                                     \
        float a_ = p[par];                                                   \
        float g_ = sigf(l[gt]);                                              \
        float m_ = fmaxf(fmaxf(fmaxf(l[c0], l[c1]), fmaxf(l[c2], l[c3])), l[c4]); \
        float e0_ = __expf(l[c0] - m_);                                      \
        float e1_ = __expf(l[c1] - m_);                                      \
        float e2_ = __expf(l[c2] - m_);                                      \
        float e3_ = __expf(l[c3] - m_);                                      \
        float e4_ = __expf(l[c4] - m_);                                      \
        float inv_ = a_ * g_ * fast_rcp(e0_ + e1_ + e2_ + e3_ + e4_);        \
        p[c0] = e0_ * inv_;                                                  \
        p[c1] = e1_ * inv_;                                                  \
        p[c2] = e2_ * inv_;                                                  \
        p[c3] = e3_ * inv_;                                                  \
        p[c4] = e4_ * inv_;                                                  \
        p[par] = a_ * (1.0f - g_);                                           \
    } while (0)

    {
        float s0_ = sigf(l[0]);
        float m_ = fmaxf(l[1], fmaxf(l[2], l[3]));
        float e1_ = __expf(l[1] - m_);
        float e2_ = __expf(l[2] - m_);
        float e3_ = __expf(l[3] - m_);
        float inv_ = s0_ * fast_rcp(e1_ + e2_ + e3_);
        p[1] = e1_ * inv_;
        p[2] = e2_ * inv_;
        p[3] = e3_ * inv_;
        p[0] = 1.0f - s0_;
    }
    BR(1, 4); BR(2, 5); BR(3, 6);
    BR(4, 7); BR(5, 8); BR(6, 9);
    BR(7, 10); BR(8, 11);
    SUB3(9, 55, 12, 13, 14);
    BR(12, 15);
    BR(13, 16); BR(14, 17);
    BR(16, 18); BR(17, 19);
    BR(18, 20); BR(19, 21);
    SUB3(15, 56, 22, 23, 24);
    SUB5(20, 57, 25, 28, 31, 34, 37);
    SUB5(21, 58, 40, 43, 46, 49, 52);
    BR(25, 26); BR(28, 29); BR(31, 32); BR(34, 35); BR(37, 38);
    BR(26, 27); BR(29, 30); BR(32, 33); BR(35, 36); BR(38, 39);
    BR(40, 41); BR(43, 44); BR(46, 47); BR(49, 50); BR(52, 53);
    BR(41, 42); BR(44, 45); BR(47, 48); BR(50, 51); BR(53, 54);

    // ---- T_fwd = p @ tfs via MFMA: p hi/lo rows (reuse logit space), A = tfs^T hi/lo ----
    {
        char* row = lds + tid * ROWB;
#pragma unroll
        for (int jj = 0; jj < 64; jj += 4) {
            float v0 = (jj + 0 < NB) ? p[jj + 0] : 0.0f;
            float v1 = (jj + 1 < NB) ? p[jj + 1] : 0.0f;
            float v2 = (jj + 2 < NB) ? p[jj + 2] : 0.0f;
            float v3 = (jj + 3 < NB) ? p[jj + 3] : 0.0f;
            unsigned hx, lx, hy, ly;
            pack2_hl(v0, v1, hx, lx);
            pack2_hl(v2, v3, hy, ly);
            uint2v hw, lw;
            hw.x = hx; hw.y = hy;
            lw.x = lx; lw.y = ly;
            *(uint2v*)(row + 2 * jj) = hw;
            *(uint2v*)(row + 128 + 2 * jj) = lw;
        }
    }
    {
        const short* Ahi_p = (const short*)(ws + WS_TFHI);
        const short* Alo_p = (const short*)(ws + WS_TFLO);
        float4v acc[4];
#pragma unroll
        for (int pt = 0; pt < 4; ++pt) acc[pt] = (float4v){0.f, 0.f, 0.f, 0.f};
#pragma unroll
        for (int k0 = 0; k0 < 64; k0 += 32) {
            short8 Bhi[4], Blo[4];
#pragma unroll
            for (int pt = 0; pt < 4; ++pt) {
                const char* rowp = lds + (mrow0 + pt * 16 + l15) * ROWB;
                Bhi[pt] = *(const short8*)(rowp + 2 * k0 + 16 * g);
                Blo[pt] = *(const short8*)(rowp + 128 + 2 * k0 + 16 * g);
            }
            short8 Ahi = *(const short8*)(Ahi_p + l15 * 64 + k0 + g * 8);
            short8 Alo = *(const short8*)(Alo_p + l15 * 64 + k0 + g * 8);
#pragma unroll
            for (int pt = 0; pt < 4; ++pt) {
                acc[pt] = mfma16(Ahi, Bhi[pt], acc[pt]);
                acc[pt] = mfma16(Ahi, Blo[pt], acc[pt]);
                acc[pt] = mfma16(Alo, Bhi[pt], acc[pt]);
            }
        }
#pragma unroll
        for (int pt = 0; pt < 4; ++pt)
            *(float4v*)(lds + (mrow0 + pt * 16 + l15) * ROWB + 256 + g * 16) = acc[pt];
    }
    float T[16];
#pragma unroll
    for (int j = 0; j < 4; ++j)
        *(float4v*)&T[4 * j] = *(const float4v*)(lds + tid * ROWB + 256 + 16 * j);

    const float xb0 = fmaf(T[0], x, fmaf(T[1], y, fmaf(T[2], z, T[3])));
    const float xb1 = fmaf(T[4], x, fmaf(T[5], y, fmaf(T[6], z, T[7])));
    const float xb2 = fmaf(T[8], x, fmaf(T[9], y, fmaf(T[10], z, T[11])));

    float qr = quats[4 * n + 0];
    float qx = quats[4 * n + 1];
    float qy = quats[4 * n + 2];
    float qz = quats[4 * n + 3];
    {
        float inv = fast_rsq(qr * qr + qx * qx + qy * qy + qz * qz);
        qr *= inv; qx *= inv; qy *= inv; qz *= inv;
    }
    const float R00 = 1.0f - 2.0f * (qy * qy + qz * qz);
    const float R01 = 2.0f * (qx * qy - qr * qz);
    const float R02 = 2.0f * (qx * qz + qr * qy);
    const float R10 = 2.0f * (qx * qy + qr * qz);
    const float R11 = 1.0f - 2.0f * (qx * qx + qz * qz);
    const float R12 = 2.0f * (qy * qz - qr * qx);
    const float R20 = 2.0f * (qx * qz - qr * qy);
    const float R21 = 2.0f * (qy * qz + qr * qx);
    const float R22 = 1.0f - 2.0f * (qx * qx + qy * qy);

    const float B00 = T[0] * R00 + T[1] * R10 + T[2] * R20;
    const float B01 = T[0] * R01 + T[1] * R11 + T[2] * R21;
    const float B02 = T[0] * R02 + T[1] * R12 + T[2] * R22;
    const float B10 = T[4] * R00 + T[5] * R10 + T[6] * R20;
    const float B11 = T[4] * R01 + T[5] * R11 + T[6] * R21;
    const float B12 = T[4] * R02 + T[5] * R12 + T[6] * R22;
    const float B20 = T[8] * R00 + T[9] * R10 + T[10] * R20;
    const float B21 = T[8] * R01 + T[9] * R11 + T[10] * R21;
    const float B22 = T[8] * R02 + T[9] * R12 + T[10] * R22;

    const float t0 = 1.0f + B00 + B11 + B22;
    const float t1 = 1.0f + B00 - B11 - B22;
    const float t2 = 1.0f - B00 + B11 - B22;
    const float t3 = 1.0f - B00 - B11 + B22;
    const float s0 = 0.5f * fast_rsq(fmaxf(t0, 1e-8f));
    const float s1 = 0.5f * fast_rsq(fmaxf(t1, 1e-8f));
    const float s2 = 0.5f * fast_rsq(fmaxf(t2, 1e-8f));
    const float s3 = 0.5f * fast_rsq(fmaxf(t3, 1e-8f));
    const float q0w = t0 * s0, q0x = (B21 - B12) * s0, q0y = (B02 - B20) * s0, q0z = (B10 - B01) * s0;
    const float q1w = (B21 - B12) * s1, q1x = t1 * s1, q1y = (B01 + B10) * s1, q1z = (B02 + B20) * s1;
    const float q2w = (B02 - B20) * s2, q2x = (B01 + B10) * s2, q2y = t2 * s2, q2z = (B12 + B21) * s2;
    const float q3w = (B10 - B01) * s3, q3x = (B02 + B20) * s3, q3y = (B12 + B21) * s3, q3z = t3 * s3;

    int best = 0;
    float tb = t0;
    if (t1 > tb) { best = 1; tb = t1; }
    if (t2 > tb) { best = 2; tb = t2; }
    if (t3 > tb) { best = 3; tb = t3; }

    float Qw = (best == 0) ? q0w : (best == 1) ? q1w : (best == 2) ? q2w : q3w;
    float Qx = (best == 0) ? q0x : (best == 1) ? q1x : (best == 2) ? q2x : q3x;
    float Qy = (best == 0) ? q0y : (best == 1) ? q1y : (best == 2) ? q2y : q3y;
    float Qz = (best == 0) ? q0z : (best == 1) ? q1z : (best == 2) ? q2z : q3z;
    {
        float inv = fast_rsq(Qw * Qw + Qx * Qx + Qy * Qy + Qz * Qz);
        Qw *= inv; Qx *= inv; Qy *= inv; Qz *= inv;
    }

    out[3 * n + 0] = xb0;
    out[3 * n + 1] = xb1;
    out[3 * n + 2] = xb2;
    float* rb = out + 3 * (size_t)NPTS;
    rb[9 * n + 0] = B00; rb[9 * n + 1] = B01; rb[9 * n + 2] = B02;
    rb[9 * n + 3] = B10; rb[9 * n + 4] = B11; rb[9 * n + 5] = B12;
    rb[9 * n + 6] = B20; rb[9 * n + 7] = B21; rb[9 * n + 8] = B22;
    float4* qb = (float4*)(out + 12 * (size_t)NPTS);
    qb[n] = make_float4(Qw, Qx, Qy, Qz);
    float4* tf = (float4*)(out + 16 * (size_t)NPTS);
    tf[4 * n + 0] = make_float4(T[0], T[1], T[2], T[3]);
    tf[4 * n + 1] = make_float4(T[4], T[5], T[6], T[7]);
    tf[4 * n + 2] = make_float4(T[8], T[9], T[10], T[11]);
    tf[4 * n + 3] = make_float4(T[12], T[13], T[14], T[15]);
}

extern "C" void kernel_launch(void* const* d_in, const int* in_sizes, int n_in,
                              void* d_out, int out_size, void* d_ws, size_t ws_size,
                              hipStream_t stream) {
    const float* xyz = (const float*)d_in[0];
    const float* quats = (const float*)d_in[1];
    const float* tfs = (const float*)d_in[2];
    const float* amn = (const float*)d_in[3];
    const float* amx = (const float*)d_in[4];
    const float* W0 = (const float*)d_in[5];
    const float* b0 = (const float*)d_in[6];
    const float* W1 = (const float*)d_in[7];
    const float* b1 = (const float*)d_in[8];
    const float* W2 = (const float*)d_in[9];
    const float* b2 = (const float*)d_in[10];
    const float* W3 = (const float*)d_in[11];
    const float* b3 = (const float*)d_in[12];
    float* out = (float*)d_out;
    char* ws = (char*)d_ws;

    hipLaunchKernelGGL(prep_kernel, dim3(64), dim3(256), 0, stream, W0, W1, W2, W3, b3, tfs, ws);
    hipLaunchKernelGGL(skin_kernel, dim3(NPTS / BLK), dim3(BLK), 0, stream,
                       xyz, quats, amn, amx, b0, b1, b2, (const char*)ws, out);
}